// Round 1
// baseline (78787.201 us; speedup 1.0000x reference)
//
#include <hip/hip_runtime.h>
#include <cstdint>
#include <cstddef>

#define TT 360
#define BFULL 512
#define HH 256
#define GH 1024   /* 4*H */

typedef unsigned short u16;
typedef short bf16x8_t __attribute__((ext_vector_type(8)));
typedef short bf16x4_t __attribute__((ext_vector_type(4)));
typedef float f32x4_t  __attribute__((ext_vector_type(4)));

__device__ __forceinline__ float bf2f(u16 u){
  union { unsigned u; float f; } v; v.u = ((unsigned)u) << 16; return v.f;
}
__device__ __forceinline__ u16 f2bf(float f){
  union { float f; unsigned u; } v; v.f = f;
  unsigned r = v.u + 0x7FFFu + ((v.u >> 16) & 1u);
  return (u16)(r >> 16);
}
__device__ __forceinline__ float sigm(float x){
  x = fminf(fmaxf(x, -30.f), 30.f);
  return 1.f / (1.f + __expf(-x));
}
__device__ __forceinline__ float tanh_(float x){
  x = fminf(fmaxf(x, -15.f), 15.f);
  float e = __expf(-2.f * x);
  return (1.f - e) / (1.f + e);
}
__device__ __forceinline__ f32x4_t cvt4(bf16x4_t v){
  f32x4_t r;
#pragma unroll
  for (int i = 0; i < 4; ++i) r[i] = bf2f((u16)v[i]);
  return r;
}

// ---------------- small prep kernels ----------------

__global__ void k_cvt_pad(const float* src, u16* dst, int N, int srcK, int useK, int Np, int Kp){
  int i = blockIdx.x * blockDim.x + threadIdx.x;
  if (i >= Np * Kp) return;
  int n = i / Kp, k = i - n * Kp;
  float v = (n < N && k < useK) ? src[(size_t)n * srcK + k] : 0.f;
  dst[i] = f2bf(v);
}

__global__ void k_bias_sum(const float* a, const float* b, float* o, int n){
  int i = blockIdx.x * blockDim.x + threadIdx.x;
  if (i < n) o[i] = a[i] + b[i];
}

__global__ void k_zero(float* p, int n){
  int i = blockIdx.x * blockDim.x + threadIdx.x;
  if (i < n) p[i] = 0.f;
}

// build xc = [x, ce, pad] (32 cols) and sx = [x shifted by 1, pad] (32 cols), bf16, group-local
__global__ void k_build(const float* x, const int* labels, const float* emb,
                        u16* xc, u16* sx, int b0, int Bg){
  int i = blockIdx.x * blockDim.x + threadIdx.x;
  if (i >= Bg * TT * 32) return;
  int col = i & 31; int bt = i >> 5;
  int t = bt % TT; int b = bt / TT;
  int gb = b0 + b;
  float xcv, sxv;
  if (col < 12)      xcv = x[((size_t)gb * TT + t) * 12 + col];
  else if (col < 20) xcv = emb[labels[gb] * 8 + (col - 12)];
  else               xcv = 0.f;
  sxv = (col < 12 && t > 0) ? x[((size_t)gb * TT + (t - 1)) * 12 + col] : 0.f;
  xc[i] = f2bf(xcv);
  sx[i] = f2bf(sxv);
}

// ---------------- projection GEMM (writes G in MFMA C-frag layout) ----------------
// C[m', n] with m' = t*Bg + b.  A is bf16 [rows][Akp] row-major with row = b*TT + t_src,
// W is bf16 [1024][K] row-major (PyTorch layout, i.e. we compute A @ W^T).
// Output G bf16 frag layout: [t][btile(Bg/16)][ntile(64)][lane(64)][4].

struct ProjArgs {
  const u16* A; const u16* W;
  const float* colbias;   // [1024] or null
  const float* rowbias;   // [Bg rows offset already applied][1024] f32 or null
  u16* G;
  int Akp, K, t0, rev, Bg, bgLog;
};

template<int BK>
__global__ __launch_bounds__(256) void k_proj(ProjArgs p){
  constexpr int SLOTS = BK / 8;
  constexpr int SM = SLOTS - 1;
  constexpr int LOG = (BK == 64) ? 3 : 2;
  __shared__ u16 lA[128 * BK];
  __shared__ u16 lW[128 * BK];
  const int tid = threadIdx.x, lane = tid & 63, wid = tid >> 6;
  const int wm = wid >> 1, wn = wid & 1;
  const int mBase = blockIdx.x * 128;
  const int nBase = blockIdx.y * 128;
  const int t_rel = mBase >> p.bgLog;
  const int bBase = mBase & (p.Bg - 1);
  const int t_glob = p.t0 + t_rel;
  const int t_src = p.rev ? (TT - 1 - t_glob) : t_glob;

  f32x4_t acc[4][4];
#pragma unroll
  for (int m = 0; m < 4; ++m)
#pragma unroll
    for (int n = 0; n < 4; ++n) acc[m][n] = (f32x4_t){0.f, 0.f, 0.f, 0.f};

  for (int k0 = 0; k0 < p.K; k0 += BK){
#pragma unroll
    for (int i = 0; i < (128 * SLOTS) / 256; ++i){
      int idx = i * 256 + tid;
      int row = idx >> LOG, sl = idx & SM;
      bf16x8_t va = *(const bf16x8_t*)(p.A + (size_t)((bBase + row) * TT + t_src) * p.Akp + k0 + sl * 8);
      *(bf16x8_t*)&lA[((row << LOG) + (sl ^ (row & SM))) * 8] = va;
      bf16x8_t vw = *(const bf16x8_t*)(p.W + (size_t)(nBase + row) * p.K + k0 + sl * 8);
      *(bf16x8_t*)&lW[((row << LOG) + (sl ^ (row & SM))) * 8] = vw;
    }
    __syncthreads();
#pragma unroll
    for (int kk = 0; kk < BK; kk += 32){
      bf16x8_t af[4], wf[4];
#pragma unroll
      for (int m = 0; m < 4; ++m){
        int row = wm * 64 + m * 16 + (lane & 15);
        int sl = ((kk >> 3) + (lane >> 4)) ^ (row & SM);
        af[m] = *(const bf16x8_t*)&lA[((row << LOG) + sl) * 8];
      }
#pragma unroll
      for (int n = 0; n < 4; ++n){
        int row = wn * 64 + n * 16 + (lane & 15);
        int sl = ((kk >> 3) + (lane >> 4)) ^ (row & SM);
        wf[n] = *(const bf16x8_t*)&lW[((row << LOG) + sl) * 8];
      }
#pragma unroll
      for (int m = 0; m < 4; ++m)
#pragma unroll
        for (int n = 0; n < 4; ++n)
          acc[m][n] = __builtin_amdgcn_mfma_f32_16x16x32_bf16(af[m], wf[n], acc[m][n], 0, 0, 0);
    }
    __syncthreads();
  }

  const int btiles = p.Bg >> 4;
#pragma unroll
  for (int m = 0; m < 4; ++m){
    int btile = (bBase + wm * 64 + m * 16) >> 4;
#pragma unroll
    for (int n = 0; n < 4; ++n){
      int coltile = nBase + wn * 64 + n * 16;
      int col = coltile + (lane & 15);
      int ntile = coltile >> 4;
      float cb = p.colbias ? p.colbias[col] : 0.f;
      bf16x4_t outv;
#pragma unroll
      for (int q = 0; q < 4; ++q){
        int r = bBase + wm * 64 + m * 16 + (lane >> 4) * 4 + q;
        float v = acc[m][n][q] + cb;
        if (p.rowbias) v += p.rowbias[(size_t)r * GH + col];
        outv[q] = (short)f2bf(v);
      }
      *(bf16x4_t*)(p.G + ((((size_t)t_rel * btiles + btile) * 64 + ntile) * 64 + lane) * 4) = outv;
    }
  }
}

// ---------------- LSTM recurrence ----------------
// Each block owns 32 batch rows of one direction; 4 waves split the 16 h-tiles (j % 4 == wave).
// h kept bf16 in swizzled LDS, c kept f32 in registers (MFMA C-frag layout).

struct RecurArgs {
  const u16* G0; const u16* G1;      // frag-layout gate inputs per dir
  const u16* W0; const u16* W1;      // Whh bf16 [1024][256] per dir
  u16* sH0; u16* sH1;                // h state bf16 [b][256] (pointer pre-offset to group)
  float* sC0; float* sC1;            // c state f32
  u16* Y;                            // output buffer or null (group-local rows)
  int ycols, yoff0, yoff1, yrev0, yrev1;
  int t0, t1, nb, Bg;
};

__global__ __launch_bounds__(256) void k_recur(RecurArgs p){
  const int blk = blockIdx.x;
  const int dir = blk / p.nb;
  const int bb = (blk % p.nb) * 32;
  const int tid = threadIdx.x, lane = tid & 63, w = tid >> 6;
  const u16* G  = dir ? p.G1 : p.G0;
  const u16* Whh = dir ? p.W1 : p.W0;
  u16* sH = dir ? p.sH1 : p.sH0;
  float* sC = dir ? p.sC1 : p.sC0;
  const int yoff = dir ? p.yoff1 : p.yoff0;
  const int yrev = dir ? p.yrev1 : p.yrev0;
  const size_t gtStride = (size_t)p.Bg * GH;   // elements per t in G

  __shared__ u16 hlds[32 * 256];

  // load h state into swizzled LDS
#pragma unroll
  for (int i = 0; i < 4; ++i){
    int idx = i * 256 + tid; int row = idx >> 5, sl = idx & 31;
    bf16x8_t v = *(const bf16x8_t*)(sH + (size_t)(bb + row) * 256 + sl * 8);
    *(bf16x8_t*)&hlds[((row << 5) + (sl ^ (row & 7))) * 8] = v;
  }
  // load c state (frag layout)
  float cfr[2][4][4];
#pragma unroll
  for (int mt = 0; mt < 2; ++mt)
#pragma unroll
    for (int jj = 0; jj < 4; ++jj){
      int col = (jj * 4 + w) * 16 + (lane & 15);
#pragma unroll
      for (int q = 0; q < 4; ++q){
        int r = bb + mt * 16 + (lane >> 4) * 4 + q;
        cfr[mt][jj][q] = sC[(size_t)r * 256 + col];
      }
    }
  __syncthreads();

  for (int s = p.t0; s < p.t1; ++s){
    // A-fragments of h(s)
    bf16x8_t af[2][8];
#pragma unroll
    for (int mt = 0; mt < 2; ++mt)
#pragma unroll
      for (int ks = 0; ks < 8; ++ks){
        int row = mt * 16 + (lane & 15);
        int sl = ((ks << 2) + (lane >> 4)) ^ (row & 7);
        af[mt][ks] = *(const bf16x8_t*)&hlds[((row << 5) + sl) * 8];
      }
    __syncthreads();  // all reads done; safe to overwrite h

    const u16* Gt = G + (size_t)(s - p.t0) * gtStride;
#pragma unroll
    for (int jj = 0; jj < 4; ++jj){
      const int j = jj * 4 + w;
      f32x4_t acc[2][4];
#pragma unroll
      for (int mt = 0; mt < 2; ++mt){
        int btile = (bb >> 4) + mt;
#pragma unroll
        for (int g = 0; g < 4; ++g){
          int ntile = g * 16 + j;
          bf16x4_t gv = *(const bf16x4_t*)(Gt + (((size_t)btile * 64 + ntile) * 64 + lane) * 4);
          acc[mt][g] = cvt4(gv);
        }
      }
#pragma unroll
      for (int ks = 0; ks < 8; ++ks){
        bf16x8_t bfr[4];
#pragma unroll
        for (int g = 0; g < 4; ++g){
          int nrow = g * 256 + j * 16 + (lane & 15);
          bfr[g] = *(const bf16x8_t*)(Whh + (size_t)nrow * 256 + (ks << 5) + ((lane >> 4) << 3));
        }
#pragma unroll
        for (int g = 0; g < 4; ++g)
#pragma unroll
          for (int mt = 0; mt < 2; ++mt)
            acc[mt][g] = __builtin_amdgcn_mfma_f32_16x16x32_bf16(af[mt][ks], bfr[g], acc[mt][g], 0, 0, 0);
      }
#pragma unroll
      for (int mt = 0; mt < 2; ++mt)
#pragma unroll
        for (int q = 0; q < 4; ++q){
          float iv = sigm(acc[mt][0][q]);
          float fv = sigm(acc[mt][1][q]);
          float gv = tanh_(acc[mt][2][q]);
          float ov = sigm(acc[mt][3][q]);
          float c = fv * cfr[mt][jj][q] + iv * gv;
          cfr[mt][jj][q] = c;
          float h = ov * tanh_(c);
          int row = mt * 16 + (lane >> 4) * 4 + q;
          int col = j * 16 + (lane & 15);
          hlds[((row << 5) + ((col >> 3) ^ (row & 7))) * 8 + (col & 7)] = f2bf(h);
        }
    }
    __syncthreads();  // h(s+1) complete

    if (p.Y){
      int ty = yrev ? (TT - 1 - s) : s;
#pragma unroll
      for (int i = 0; i < 4; ++i){
        int idx = i * 256 + tid; int row = idx >> 5, sl = idx & 31;
        bf16x8_t v = *(const bf16x8_t*)&hlds[((row << 5) + (sl ^ (row & 7))) * 8];
        *(bf16x8_t*)(p.Y + ((size_t)(bb + row) * TT + ty) * p.ycols + yoff + sl * 8) = v;
      }
    }
  }

  // write back states
#pragma unroll
  for (int i = 0; i < 4; ++i){
    int idx = i * 256 + tid; int row = idx >> 5, sl = idx & 31;
    bf16x8_t v = *(const bf16x8_t*)&hlds[((row << 5) + (sl ^ (row & 7))) * 8];
    *(bf16x8_t*)(sH + (size_t)(bb + row) * 256 + sl * 8) = v;
  }
#pragma unroll
  for (int mt = 0; mt < 2; ++mt)
#pragma unroll
    for (int jj = 0; jj < 4; ++jj){
      int col = (jj * 4 + w) * 16 + (lane & 15);
#pragma unroll
      for (int q = 0; q < 4; ++q){
        int r = bb + mt * 16 + (lane >> 4) * 4 + q;
        sC[(size_t)r * 256 + col] = cfr[mt][jj][q];
      }
    }
}

// ---------------- mid / epilogue kernels (full batch, small) ----------------

__global__ void k_mulv(const u16* sH0, const u16* sH1,
                       const float* Wmu, const float* bmu,
                       const float* Wlv, const float* blv, float* mulv){
  int i = blockIdx.x * blockDim.x + threadIdx.x;
  if (i >= BFULL * 128) return;
  int b = i >> 7, j = i & 127;
  const float* W = (j < 64) ? (Wmu + (size_t)j * 512) : (Wlv + (size_t)(j - 64) * 512);
  float s = (j < 64) ? bmu[j] : blv[j - 64];
  for (int k = 0; k < 256; ++k) s += bf2f(sH0[(size_t)b * 256 + k]) * W[k];
  for (int k = 0; k < 256; ++k) s += bf2f(sH1[(size_t)b * 256 + k]) * W[256 + k];
  mulv[i] = s;
}

__global__ void k_sample(const float* mulv, const float* eps, const int* labels, const float* emb,
                         float* out_mu, float* out_lv, float* out_z, float* zcf){
  int i = blockIdx.x * blockDim.x + threadIdx.x;
  if (i >= BFULL * 128) return;
  int b = i >> 7, j = i & 127;
  if (j < 64){
    float mu = mulv[b * 128 + j];
    float lv = mulv[b * 128 + 64 + j];
    float z = mu + eps[b * 64 + j] * __expf(0.5f * lv);
    out_mu[b * 64 + j] = mu;
    out_lv[b * 64 + j] = lv;
    out_z[b * 64 + j] = z;
    zcf[i] = z;
  } else if (j < 72){
    zcf[i] = emb[labels[b] * 8 + (j - 64)];
  } else {
    zcf[i] = 0.f;
  }
}

__global__ void k_hc(const float* zcf, const float* Whid, const float* bhid,
                     const float* Wcell, const float* bcell, float* HC){
  int i = blockIdx.x * blockDim.x + threadIdx.x;
  if (i >= BFULL * 1024) return;
  int b = i >> 10, n = i & 1023;
  const float* W; float s;
  if (n < 512){ W = Whid + (size_t)n * 72; s = bhid[n]; }
  else        { W = Wcell + (size_t)(n - 512) * 72; s = bcell[n - 512]; }
  for (int k = 0; k < 72; ++k) s += zcf[b * 128 + k] * W[k];
  HC[i] = s;
}

__global__ void k_zconst(const float* zcf, const float* dWih0,
                         const float* dbih0, const float* dbhh0, float* zconst){
  int i = blockIdx.x * blockDim.x + threadIdx.x;
  if (i >= BFULL * 1024) return;
  int b = i >> 10, n = i & 1023;
  float s = dbih0[n] + dbhh0[n];
  const float* W = dWih0 + (size_t)n * 84 + 12;
  for (int k = 0; k < 72; ++k) s += zcf[b * 128 + k] * W[k];
  zconst[i] = s;
}

// faithful torch .view(NL, B, H) on [B, NL*H]
__global__ void k_dec_init(const float* HC, u16* h0, float* c0, u16* h1, float* c1){
  int i = blockIdx.x * blockDim.x + threadIdx.x;
  if (i >= BFULL * 256) return;
  int b = i >> 8, h = i & 255;
  int col = (b & 1) * 256 + h;
  int r0 = b >> 1;
  int r1 = 256 + (b >> 1);
  h0[i] = f2bf(HC[(size_t)r0 * 1024 + col]);
  c0[i] =      HC[(size_t)r0 * 1024 + 512 + col];
  h1[i] = f2bf(HC[(size_t)r1 * 1024 + col]);
  c1[i] =      HC[(size_t)r1 * 1024 + 512 + col];
}

__global__ __launch_bounds__(256) void k_out(const u16* y1d, const u16* Wo, const float* bout, float* out){
  const int tid = threadIdx.x, lane = tid & 63, w = tid >> 6;
  const size_t rbase = (size_t)blockIdx.x * 256 + w * 64;
  f32x4_t acc[4];
#pragma unroll
  for (int mt = 0; mt < 4; ++mt) acc[mt] = (f32x4_t){0.f, 0.f, 0.f, 0.f};
#pragma unroll
  for (int ks = 0; ks < 8; ++ks){
    bf16x8_t wf = *(const bf16x8_t*)(Wo + (size_t)(lane & 15) * 256 + (ks << 5) + ((lane >> 4) << 3));
#pragma unroll
    for (int mt = 0; mt < 4; ++mt){
      bf16x8_t af = *(const bf16x8_t*)(y1d + (rbase + mt * 16 + (lane & 15)) * 256 + (ks << 5) + ((lane >> 4) << 3));
      acc[mt] = __builtin_amdgcn_mfma_f32_16x16x32_bf16(af, wf, acc[mt], 0, 0, 0);
    }
  }
  int col = lane & 15;
  if (col < 12){
    float bb = bout[col];
#pragma unroll
    for (int mt = 0; mt < 4; ++mt)
#pragma unroll
      for (int q = 0; q < 4; ++q){
        size_t r = rbase + mt * 16 + (lane >> 4) * 4 + q;
        out[r * 12 + col] = acc[mt][q] + bb;
      }
  }
}

// ---------------- host ----------------

static inline size_t alignup(size_t x){ return (x + 255) & ~(size_t)255; }

extern "C" void kernel_launch(void* const* d_in, const int* in_sizes, int n_in,
                              void* d_out, int out_size, void* d_ws, size_t ws_size,
                              hipStream_t stream){
  const float* x      = (const float*)d_in[0];
  const int*   labels = (const int*)  d_in[1];
  const float* eps    = (const float*)d_in[2];
  const float* emb    = (const float*)d_in[3];
  const float* Wih0f = (const float*)d_in[4],  *Whh0f = (const float*)d_in[5];
  const float* bih0f = (const float*)d_in[6],  *bhh0f = (const float*)d_in[7];
  const float* Wih0b = (const float*)d_in[8],  *Whh0b = (const float*)d_in[9];
  const float* bih0b = (const float*)d_in[10], *bhh0b = (const float*)d_in[11];
  const float* Wih1f = (const float*)d_in[12], *Whh1f = (const float*)d_in[13];
  const float* bih1f = (const float*)d_in[14], *bhh1f = (const float*)d_in[15];
  const float* Wih1b = (const float*)d_in[16], *Whh1b = (const float*)d_in[17];
  const float* bih1b = (const float*)d_in[18], *bhh1b = (const float*)d_in[19];
  const float* Wmu = (const float*)d_in[20], *bmu = (const float*)d_in[21];
  const float* Wlv = (const float*)d_in[22], *blv = (const float*)d_in[23];
  const float* Whid = (const float*)d_in[24], *bhid = (const float*)d_in[25];
  const float* Wcell = (const float*)d_in[26], *bcell = (const float*)d_in[27];
  const float* dWih0 = (const float*)d_in[28], *dWhh0 = (const float*)d_in[29];
  const float* dbih0 = (const float*)d_in[30], *dbhh0 = (const float*)d_in[31];
  const float* dWih1 = (const float*)d_in[32], *dWhh1 = (const float*)d_in[33];
  const float* dbih1 = (const float*)d_in[34], *dbhh1 = (const float*)d_in[35];
  const float* Wout = (const float*)d_in[36], *bout = (const float*)d_in[37];

  float* out = (float*)d_out;
  float* out_mu = out + (size_t)BFULL * TT * 12;
  float* out_lv = out_mu + (size_t)BFULL * 64;
  float* out_z  = out_lv + (size_t)BFULL * 64;

  // ---- pick batch-group size Bg and T-chunk Tc to fit ws ----
  int Bg = 512, bgLog = 9, Tc = 8;
  for (int cand = 512; cand >= 128; cand >>= 1){
    size_t fixedB = 0;
    fixedB += alignup((size_t)4 * 1024 * 1024);                 // weights + biases (generous)
    fixedB += 2 * alignup((size_t)cand * TT * 32 * 2);          // xc, sx
    fixedB += alignup((size_t)cand * TT * 512 * 2);             // y0
    fixedB += 2 * alignup((size_t)cand * TT * 256 * 2);         // y0d, y1d
    fixedB += alignup((size_t)16 * 1024 * 1024);                // full-batch small buffers
    size_t need8 = fixedB + 2 * alignup((size_t)8 * cand * GH * 2);
    if (need8 <= ws_size){
      Bg = cand;
      bgLog = (cand == 512) ? 9 : (cand == 256 ? 8 : 7);
      size_t perT = 2 * (size_t)cand * GH * 2;
      size_t tcmax = (ws_size - fixedB) / perT;
      Tc = (int)((tcmax > TT) ? TT : tcmax);
      if (Tc < 1) Tc = 1;
      break;
    }
    if (cand == 128){ Bg = 128; bgLog = 7; Tc = 1; }  // last resort
  }
  const int nGroups = BFULL / Bg;
  const int nb = Bg / 32;

  // ---- ws layout ----
  char* ws = (char*)d_ws; size_t off = 0;
  auto alloc = [&](size_t bytes)->char*{ char* p = ws + off; off += alignup(bytes); return p; };

  u16* W0f_b  = (u16*)alloc(1024 * 32 * 2);
  u16* W0b_b  = (u16*)alloc(1024 * 32 * 2);
  u16* dWx_b  = (u16*)alloc(1024 * 32 * 2);
  u16* Wo_b   = (u16*)alloc(16 * 256 * 2);
  u16* Whh0f_b = (u16*)alloc(1024 * 256 * 2);
  u16* Whh0b_b = (u16*)alloc(1024 * 256 * 2);
  u16* Whh1f_b = (u16*)alloc(1024 * 256 * 2);
  u16* Whh1b_b = (u16*)alloc(1024 * 256 * 2);
  u16* dWhh0_b = (u16*)alloc(1024 * 256 * 2);
  u16* dWhh1_b = (u16*)alloc(1024 * 256 * 2);
  u16* dWih1_b = (u16*)alloc(1024 * 256 * 2);
  u16* Wih1f_b = (u16*)alloc(1024 * 512 * 2);
  u16* Wih1b_b = (u16*)alloc(1024 * 512 * 2);
  float* b0f = (float*)alloc(1024 * 4);
  float* b0b = (float*)alloc(1024 * 4);
  float* b1f = (float*)alloc(1024 * 4);
  float* b1b = (float*)alloc(1024 * 4);
  float* db1 = (float*)alloc(1024 * 4);
  // full-batch state / mid buffers
  u16*  sHe0 = (u16*)alloc((size_t)2 * BFULL * 256 * 2);
  float* sCe0 = (float*)alloc((size_t)2 * BFULL * 256 * 4);
  u16*  sHe1 = (u16*)alloc((size_t)2 * BFULL * 256 * 2);
  float* sCe1 = (float*)alloc((size_t)2 * BFULL * 256 * 4);
  u16*  dh0 = (u16*)alloc((size_t)BFULL * 256 * 2);
  float* dc0 = (float*)alloc((size_t)BFULL * 256 * 4);
  u16*  dh1 = (u16*)alloc((size_t)BFULL * 256 * 2);
  float* dc1 = (float*)alloc((size_t)BFULL * 256 * 4);
  float* mulv = (float*)alloc((size_t)BFULL * 128 * 4);
  float* zcf  = (float*)alloc((size_t)BFULL * 128 * 4);
  float* HC   = (float*)alloc((size_t)BFULL * 1024 * 4);
  float* zconst = (float*)alloc((size_t)BFULL * 1024 * 4);
  // group buffers
  u16* xc  = (u16*)alloc((size_t)Bg * TT * 32 * 2);
  u16* sx  = (u16*)alloc((size_t)Bg * TT * 32 * 2);
  u16* y0  = (u16*)alloc((size_t)Bg * TT * 512 * 2);
  u16* y0d = (u16*)alloc((size_t)Bg * TT * 256 * 2);
  u16* y1d = (u16*)alloc((size_t)Bg * TT * 256 * 2);
  u16* Gf  = (u16*)alloc((size_t)Tc * Bg * GH * 2);
  u16* Gb  = (u16*)alloc((size_t)Tc * Bg * GH * 2);

  auto cvt = [&](const float* src, u16* dst, int N, int srcK, int useK, int Np, int Kp){
    int tot = Np * Kp;
    k_cvt_pad<<<(tot + 255) / 256, 256, 0, stream>>>(src, dst, N, srcK, useK, Np, Kp);
  };
  auto bsum = [&](const float* a, const float* b, float* o){
    k_bias_sum<<<4, 256, 0, stream>>>(a, b, o, 1024);
  };
  auto zero = [&](void* p, size_t nf){
    k_zero<<<(int)((nf + 255) / 256), 256, 0, stream>>>((float*)p, (int)nf);
  };
  auto proj = [&](int BK, const u16* A, int Akp, int K, const u16* W, const float* cb,
                  const float* rb, u16* G, int t0, int tc, int rev){
    ProjArgs pa; pa.A = A; pa.W = W; pa.colbias = cb; pa.rowbias = rb; pa.G = G;
    pa.Akp = Akp; pa.K = K; pa.t0 = t0; pa.rev = rev; pa.Bg = Bg; pa.bgLog = bgLog;
    dim3 grid(tc * (Bg / 128), 8);
    if (BK == 32) k_proj<32><<<grid, 256, 0, stream>>>(pa);
    else          k_proj<64><<<grid, 256, 0, stream>>>(pa);
  };
  auto recur = [&](int ndir, const u16* G0p, const u16* G1p, const u16* W0p, const u16* W1p,
                   u16* sH0p, u16* sH1p, float* sC0p, float* sC1p,
                   u16* Y, int ycols, int yo0, int yo1, int yr0, int yr1, int t0, int t1){
    RecurArgs ra; ra.G0 = G0p; ra.G1 = G1p; ra.W0 = W0p; ra.W1 = W1p;
    ra.sH0 = sH0p; ra.sH1 = sH1p; ra.sC0 = sC0p; ra.sC1 = sC1p;
    ra.Y = Y; ra.ycols = ycols; ra.yoff0 = yo0; ra.yoff1 = yo1; ra.yrev0 = yr0; ra.yrev1 = yr1;
    ra.t0 = t0; ra.t1 = t1; ra.nb = nb; ra.Bg = Bg;
    k_recur<<<ndir * nb, 256, 0, stream>>>(ra);
  };

  // ---- weight prep ----
  cvt(Wih0f, W0f_b, 1024, 20, 20, 1024, 32);
  cvt(Wih0b, W0b_b, 1024, 20, 20, 1024, 32);
  cvt(dWih0, dWx_b, 1024, 84, 12, 1024, 32);
  cvt(Wout,  Wo_b,  12, 256, 256, 16, 256);
  cvt(Whh0f, Whh0f_b, 1024, 256, 256, 1024, 256);
  cvt(Whh0b, Whh0b_b, 1024, 256, 256, 1024, 256);
  cvt(Whh1f, Whh1f_b, 1024, 256, 256, 1024, 256);
  cvt(Whh1b, Whh1b_b, 1024, 256, 256, 1024, 256);
  cvt(dWhh0, dWhh0_b, 1024, 256, 256, 1024, 256);
  cvt(dWhh1, dWhh1_b, 1024, 256, 256, 1024, 256);
  cvt(dWih1, dWih1_b, 1024, 256, 256, 1024, 256);
  cvt(Wih1f, Wih1f_b, 1024, 512, 512, 1024, 512);
  cvt(Wih1b, Wih1b_b, 1024, 512, 512, 1024, 512);
  bsum(bih0f, bhh0f, b0f);
  bsum(bih0b, bhh0b, b0b);
  bsum(bih1f, bhh1f, b1f);
  bsum(bih1b, bhh1b, b1b);
  bsum(dbih1, dbhh1, db1);

  zero(sHe0, (size_t)2 * BFULL * 256 / 2);
  zero(sCe0, (size_t)2 * BFULL * 256);
  zero(sHe1, (size_t)2 * BFULL * 256 / 2);
  zero(sCe1, (size_t)2 * BFULL * 256);

  // ---- encoder (per batch group) ----
  for (int g = 0; g < nGroups; ++g){
    int b0 = g * Bg;
    k_build<<<(Bg * TT * 32) / 256, 256, 0, stream>>>(x, labels, emb, xc, sx, b0, Bg);
    u16* h0p = sHe0 + (size_t)b0 * 256;
    u16* h1p = sHe0 + (size_t)BFULL * 256 + (size_t)b0 * 256;
    float* c0p = sCe0 + (size_t)b0 * 256;
    float* c1p = sCe0 + (size_t)BFULL * 256 + (size_t)b0 * 256;
    for (int t0 = 0; t0 < TT; t0 += Tc){
      int t1 = (t0 + Tc < TT) ? t0 + Tc : TT; int tc = t1 - t0;
      proj(32, xc, 32, 32, W0f_b, b0f, nullptr, Gf, t0, tc, 0);
      proj(32, xc, 32, 32, W0b_b, b0b, nullptr, Gb, t0, tc, 1);
      recur(2, Gf, Gb, Whh0f_b, Whh0b_b, h0p, h1p, c0p, c1p,
            y0, 512, 0, 256, 0, 1, t0, t1);
    }
    u16* h0q = sHe1 + (size_t)b0 * 256;
    u16* h1q = sHe1 + (size_t)BFULL * 256 + (size_t)b0 * 256;
    float* c0q = sCe1 + (size_t)b0 * 256;
    float* c1q = sCe1 + (size_t)BFULL * 256 + (size_t)b0 * 256;
    for (int t0 = 0; t0 < TT; t0 += Tc){
      int t1 = (t0 + Tc < TT) ? t0 + Tc : TT; int tc = t1 - t0;
      proj(64, y0, 512, 512, Wih1f_b, b1f, nullptr, Gf, t0, tc, 0);
      proj(64, y0, 512, 512, Wih1b_b, b1b, nullptr, Gb, t0, tc, 1);
      recur(2, Gf, Gb, Whh1f_b, Whh1b_b, h0q, h1q, c0q, c1q,
            nullptr, 512, 0, 0, 0, 0, t0, t1);
    }
  }

  // ---- VAE head + decoder init (full batch) ----
  k_mulv<<<(BFULL * 128) / 256, 256, 0, stream>>>(sHe1, sHe1 + (size_t)BFULL * 256,
                                                  Wmu, bmu, Wlv, blv, mulv);
  k_sample<<<(BFULL * 128) / 256, 256, 0, stream>>>(mulv, eps, labels, emb,
                                                    out_mu, out_lv, out_z, zcf);
  k_hc<<<(BFULL * 1024) / 256, 256, 0, stream>>>(zcf, Whid, bhid, Wcell, bcell, HC);
  k_zconst<<<(BFULL * 1024) / 256, 256, 0, stream>>>(zcf, dWih0, dbih0, dbhh0, zconst);
  k_dec_init<<<(BFULL * 256) / 256, 256, 0, stream>>>(HC, dh0, dc0, dh1, dc1);

  // ---- decoder (per batch group) ----
  for (int g = 0; g < nGroups; ++g){
    int b0 = g * Bg;
    k_build<<<(Bg * TT * 32) / 256, 256, 0, stream>>>(x, labels, emb, xc, sx, b0, Bg);
    for (int t0 = 0; t0 < TT; t0 += Tc){
      int t1 = (t0 + Tc < TT) ? t0 + Tc : TT; int tc = t1 - t0;
      proj(32, sx, 32, 32, dWx_b, nullptr, zconst + (size_t)b0 * GH, Gf, t0, tc, 0);
      recur(1, Gf, nullptr, dWhh0_b, nullptr,
            dh0 + (size_t)b0 * 256, nullptr, dc0 + (size_t)b0 * 256, nullptr,
            y0d, 256, 0, 0, 0, 0, t0, t1);
    }
    for (int t0 = 0; t0 < TT; t0 += Tc){
      int t1 = (t0 + Tc < TT) ? t0 + Tc : TT; int tc = t1 - t0;
      proj(64, y0d, 256, 256, dWih1_b, db1, nullptr, Gf, t0, tc, 0);
      recur(1, Gf, nullptr, dWhh1_b, nullptr,
            dh1 + (size_t)b0 * 256, nullptr, dc1 + (size_t)b0 * 256, nullptr,
            y1d, 256, 0, 0, 0, 0, t0, t1);
    }
    k_out<<<(Bg * TT) / 256, 256, 0, stream>>>(y1d, Wo_b, bout, out + (size_t)b0 * TT * 12);
  }
}

// Round 2
// 34342.969 us; speedup vs baseline: 2.2941x; 2.2941x over previous
//
#include <hip/hip_runtime.h>
#include <cstdint>
#include <cstddef>

#define TT 360
#define BFULL 512
#define GH 1024   /* 4*H */

typedef unsigned short u16;
typedef short bf16x8_t __attribute__((ext_vector_type(8)));
typedef short bf16x4_t __attribute__((ext_vector_type(4)));
typedef float f32x4_t  __attribute__((ext_vector_type(4)));

__device__ __forceinline__ float bf2f(u16 u){
  union { unsigned u; float f; } v; v.u = ((unsigned)u) << 16; return v.f;
}
__device__ __forceinline__ u16 f2bf(float f){
  union { float f; unsigned u; } v; v.f = f;
  unsigned r = v.u + 0x7FFFu + ((v.u >> 16) & 1u);
  return (u16)(r >> 16);
}
__device__ __forceinline__ float sigm(float x){
  x = fminf(fmaxf(x, -30.f), 30.f);
  return 1.f / (1.f + __expf(-x));
}
__device__ __forceinline__ float tanh_(float x){
  x = fminf(fmaxf(x, -15.f), 15.f);
  float e = __expf(-2.f * x);
  return (1.f - e) / (1.f + e);
}
__device__ __forceinline__ f32x4_t cvt4(bf16x4_t v){
  f32x4_t r;
#pragma unroll
  for (int i = 0; i < 4; ++i) r[i] = bf2f((u16)v[i]);
  return r;
}

// ---------------- small prep kernels ----------------

__global__ void k_cvt_pad(const float* src, u16* dst, int N, int srcK, int useK, int Np, int Kp){
  int i = blockIdx.x * blockDim.x + threadIdx.x;
  if (i >= Np * Kp) return;
  int n = i / Kp, k = i - n * Kp;
  float v = (n < N && k < useK) ? src[(size_t)n * srcK + k] : 0.f;
  dst[i] = f2bf(v);
}

__global__ void k_bias_sum(const float* a, const float* b, float* o, int n){
  int i = blockIdx.x * blockDim.x + threadIdx.x;
  if (i < n) o[i] = a[i] + b[i];
}

__global__ void k_zero(float* p, int n){
  int i = blockIdx.x * blockDim.x + threadIdx.x;
  if (i < n) p[i] = 0.f;
}

// ---------------- projection GEMM (writes G in MFMA C-frag layout) ----------------
// G frag layout: [t][btile(Bg/16)][ntile(64)][lane(64)][4] bf16.

struct ProjArgs {
  const u16* A; const u16* W;
  const float* colbias;   // [1024] or null
  u16* G;
  int Akp, K, t0, rev, Bg, bgLog;
};

template<int BK>
__global__ __launch_bounds__(256) void k_proj(ProjArgs p){
  constexpr int SLOTS = BK / 8;
  constexpr int SM = SLOTS - 1;
  constexpr int LOG = (BK == 64) ? 3 : 2;
  __shared__ __align__(16) u16 lA[128 * BK];
  __shared__ __align__(16) u16 lW[128 * BK];
  const int tid = threadIdx.x, lane = tid & 63, wid = tid >> 6;
  const int wm = wid >> 1, wn = wid & 1;
  const int mBase = blockIdx.x * 128;
  const int nBase = blockIdx.y * 128;
  const int t_rel = mBase >> p.bgLog;
  const int bBase = mBase & (p.Bg - 1);
  const int t_glob = p.t0 + t_rel;
  const int t_src = p.rev ? (TT - 1 - t_glob) : t_glob;

  f32x4_t acc[4][4];
#pragma unroll
  for (int m = 0; m < 4; ++m)
#pragma unroll
    for (int n = 0; n < 4; ++n) acc[m][n] = (f32x4_t){0.f, 0.f, 0.f, 0.f};

  for (int k0 = 0; k0 < p.K; k0 += BK){
#pragma unroll
    for (int i = 0; i < (128 * SLOTS) / 256; ++i){
      int idx = i * 256 + tid;
      int row = idx >> LOG, sl = idx & SM;
      bf16x8_t va = *(const bf16x8_t*)(p.A + (size_t)((bBase + row) * TT + t_src) * p.Akp + k0 + sl * 8);
      *(bf16x8_t*)&lA[((row << LOG) + (sl ^ (row & SM))) * 8] = va;
      bf16x8_t vw = *(const bf16x8_t*)(p.W + (size_t)(nBase + row) * p.K + k0 + sl * 8);
      *(bf16x8_t*)&lW[((row << LOG) + (sl ^ (row & SM))) * 8] = vw;
    }
    __syncthreads();
#pragma unroll
    for (int kk = 0; kk < BK; kk += 32){
      bf16x8_t af[4], wf[4];
#pragma unroll
      for (int m = 0; m < 4; ++m){
        int row = wm * 64 + m * 16 + (lane & 15);
        int sl = ((kk >> 3) + (lane >> 4)) ^ (row & SM);
        af[m] = *(const bf16x8_t*)&lA[((row << LOG) + sl) * 8];
      }
#pragma unroll
      for (int n = 0; n < 4; ++n){
        int row = wn * 64 + n * 16 + (lane & 15);
        int sl = ((kk >> 3) + (lane >> 4)) ^ (row & SM);
        wf[n] = *(const bf16x8_t*)&lW[((row << LOG) + sl) * 8];
      }
#pragma unroll
      for (int m = 0; m < 4; ++m)
#pragma unroll
        for (int n = 0; n < 4; ++n)
          acc[m][n] = __builtin_amdgcn_mfma_f32_16x16x32_bf16(af[m], wf[n], acc[m][n], 0, 0, 0);
    }
    __syncthreads();
  }

  const int btiles = p.Bg >> 4;
#pragma unroll
  for (int m = 0; m < 4; ++m){
    int btile = (bBase + wm * 64 + m * 16) >> 4;
#pragma unroll
    for (int n = 0; n < 4; ++n){
      int coltile = nBase + wn * 64 + n * 16;
      int col = coltile + (lane & 15);
      int ntile = coltile >> 4;
      float cb = p.colbias ? p.colbias[col] : 0.f;
      bf16x4_t outv;
#pragma unroll
      for (int q = 0; q < 4; ++q)
        outv[q] = (short)f2bf(acc[m][n][q] + cb);
      *(bf16x4_t*)(p.G + ((((size_t)t_rel * btiles + btile) * 64 + ntile) * 64 + lane) * 4) = outv;
    }
  }
}

// ---------------- fused-input recurrence (enc-l0, dec-l0) ----------------
// 512 threads = 8 waves; 32 batch rows per block. Wave w owns h-col tiles jt in {w, w+8};
// ntile(jj,g) = g*16 + w + 8*jj. Small input W (K=32) resident in VGPRs; Whh streamed from L2.
// h double-buffered in swizzled LDS (one barrier/step); c state f32 in registers.

struct RXArgs {
  const float* x;           // [BFULL][TT][12]
  const int* labels;        // ENC
  const float* emb;         // ENC
  const u16* zcF;           // DEC: frag-layout zconst bf16, pre-offset to group
  const float* cb0; const float* cb1;  // ENC col-bias per dir
  const u16* Wx0; const u16* Wx1;      // [1024][32] bf16 per dir
  const u16* Wh0; const u16* Wh1;      // Whh [1024][256] bf16 per dir
  const u16* dh; const float* dc;      // DEC init state (pre-offset to group)
  u16* Y;                   // group-local output [row][TT][ycols]
  int ycols, yoff0, yoff1, gb0, nb;
};

template<int DEC>
__global__ __launch_bounds__(512, 2) void k_rx(RXArgs a){
  const int bx = blockIdx.x;
  const int dir = DEC ? 0 : (bx / a.nb);
  const int bb = (bx - dir * a.nb) * 32;
  const int tid = threadIdx.x;
  const int lane = tid & 63, w = tid >> 6;
  const int l15 = lane & 15, lhi = lane >> 4;
  const u16* Wx  = dir ? a.Wx1 : a.Wx0;
  const u16* Whh = dir ? a.Wh1 : a.Wh0;
  const float* cb = dir ? a.cb1 : a.cb0;
  const int yoff = dir ? a.yoff1 : a.yoff0;

  __shared__ __align__(16) u16 hlds[2][32 * 256];
  __shared__ __align__(16) u16 xT[2][32 * 32];

  // resident small-W B-fragments (K=32 -> one MFMA per tile)
  bf16x8_t wfx[2][4];
#pragma unroll
  for (int jj = 0; jj < 2; ++jj)
#pragma unroll
    for (int g = 0; g < 4; ++g){
      int n = g * 256 + (w + 8 * jj) * 16 + l15;
      wfx[jj][g] = *(const bf16x8_t*)(Wx + (size_t)n * 32 + (lhi << 3));
    }

  float cbf[2][4];
  float cfr[2][2][4];
  if (DEC){
#pragma unroll
    for (int mt = 0; mt < 2; ++mt)
#pragma unroll
      for (int jj = 0; jj < 2; ++jj){
        int col = (w + 8 * jj) * 16 + l15;
#pragma unroll
        for (int q = 0; q < 4; ++q)
          cfr[mt][jj][q] = a.dc[(size_t)(bb + mt * 16 + lhi * 4 + q) * 256 + col];
      }
  } else {
#pragma unroll
    for (int jj = 0; jj < 2; ++jj)
#pragma unroll
      for (int g = 0; g < 4; ++g)
        cbf[jj][g] = cb[g * 256 + (w + 8 * jj) * 16 + l15];
#pragma unroll
    for (int mt = 0; mt < 2; ++mt)
#pragma unroll
      for (int jj = 0; jj < 2; ++jj)
#pragma unroll
        for (int q = 0; q < 4; ++q) cfr[mt][jj][q] = 0.f;
  }

  // init h LDS buffer 0
  if (DEC){
#pragma unroll
    for (int i = 0; i < 2; ++i){
      int idx = i * 512 + tid;
      int row = idx >> 5, sl = idx & 31;
      bf16x8_t v = *(const bf16x8_t*)(a.dh + (size_t)(bb + row) * 256 + sl * 8);
      *(bf16x8_t*)&hlds[0][((row << 5) + (sl ^ (row & 7))) * 8] = v;
    }
  } else {
    bf16x8_t z = (bf16x8_t){0,0,0,0,0,0,0,0};
#pragma unroll
    for (int i = 0; i < 2; ++i)
      *(bf16x8_t*)&hlds[0][(i * 512 + tid) * 8] = z;
  }

  // init xT: const cols in both buffers, x cols for step 0 in buffer 0
  {
    int row = tid >> 4, c16 = tid & 15;
    int gr = a.gb0 + bb + row;
    u16 vA = 0, vB = 0;  // vA: col c16 in [12,16); vB: col 16+c16
    if (!DEC){
      int lb = a.labels[gr];
      if (c16 >= 12) vA = f2bf(a.emb[lb * 8 + (c16 - 12)]);
      if (c16 < 4)   vB = f2bf(a.emb[lb * 8 + 4 + c16]);
    }
    u16 x0 = 0;
    if (!DEC && c16 < 12){
      int t0src = dir ? (TT - 1) : 0;
      x0 = f2bf(a.x[((size_t)gr * TT + t0src) * 12 + c16]);
    }
    xT[0][row * 32 + c16] = (c16 < 12) ? x0 : vA;
    xT[1][row * 32 + c16] = (c16 < 12) ? (u16)0 : vA;
    xT[0][row * 32 + 16 + c16] = vB;
    xT[1][row * 32 + 16 + c16] = vB;
  }
  __syncthreads();

  for (int s = 0; s < TT; ++s){
    const int cur = s & 1, nxt = cur ^ 1;
    f32x4_t acc[2][2][4];
    if (DEC){
#pragma unroll
      for (int mt = 0; mt < 2; ++mt)
#pragma unroll
        for (int jj = 0; jj < 2; ++jj)
#pragma unroll
          for (int g = 0; g < 4; ++g){
            int ntile = g * 16 + w + 8 * jj;
            int btile = (bb >> 4) + mt;
            bf16x4_t gv = *(const bf16x4_t*)(a.zcF + (((size_t)btile * 64 + ntile) * 64 + lane) * 4);
            acc[mt][jj][g] = cvt4(gv);
          }
    } else {
#pragma unroll
      for (int mt = 0; mt < 2; ++mt)
#pragma unroll
        for (int jj = 0; jj < 2; ++jj)
#pragma unroll
          for (int g = 0; g < 4; ++g){
            float b = cbf[jj][g];
            acc[mt][jj][g] = (f32x4_t){b, b, b, b};
          }
    }
    // input-projection MFMA (K=32)
    {
      bf16x8_t ax0 = *(const bf16x8_t*)&xT[cur][(l15) * 32 + (lhi << 3)];
      bf16x8_t ax1 = *(const bf16x8_t*)&xT[cur][(16 + l15) * 32 + (lhi << 3)];
#pragma unroll
      for (int jj = 0; jj < 2; ++jj)
#pragma unroll
        for (int g = 0; g < 4; ++g){
          acc[0][jj][g] = __builtin_amdgcn_mfma_f32_16x16x32_bf16(ax0, wfx[jj][g], acc[0][jj][g], 0, 0, 0);
          acc[1][jj][g] = __builtin_amdgcn_mfma_f32_16x16x32_bf16(ax1, wfx[jj][g], acc[1][jj][g], 0, 0, 0);
        }
    }
    // Whh stream (K=256)
#pragma unroll
    for (int ks = 0; ks < 8; ++ks){
      int sl = ks * 4 + lhi;
      bf16x8_t af0 = *(const bf16x8_t*)&hlds[cur][((l15 << 5) + (sl ^ (l15 & 7))) * 8];
      int r1 = 16 + l15;
      bf16x8_t af1 = *(const bf16x8_t*)&hlds[cur][((r1 << 5) + (sl ^ (r1 & 7))) * 8];
      bf16x8_t bfr[2][4];
#pragma unroll
      for (int jj = 0; jj < 2; ++jj)
#pragma unroll
        for (int g = 0; g < 4; ++g)
          bfr[jj][g] = *(const bf16x8_t*)(Whh + (size_t)(g * 256 + (w + 8 * jj) * 16 + l15) * 256 + ks * 32 + (lhi << 3));
#pragma unroll
      for (int jj = 0; jj < 2; ++jj)
#pragma unroll
        for (int g = 0; g < 4; ++g){
          acc[0][jj][g] = __builtin_amdgcn_mfma_f32_16x16x32_bf16(af0, bfr[jj][g], acc[0][jj][g], 0, 0, 0);
          acc[1][jj][g] = __builtin_amdgcn_mfma_f32_16x16x32_bf16(af1, bfr[jj][g], acc[1][jj][g], 0, 0, 0);
        }
    }
    // activations + h/c update + output write
    int ty = (!DEC && dir) ? (TT - 1 - s) : s;
#pragma unroll
    for (int mt = 0; mt < 2; ++mt)
#pragma unroll
      for (int jj = 0; jj < 2; ++jj){
        int colb = (w + 8 * jj) * 16 + l15;
#pragma unroll
        for (int q = 0; q < 4; ++q){
          float iv = sigm(acc[mt][jj][0][q]);
          float fv = sigm(acc[mt][jj][1][q]);
          float gv = tanh_(acc[mt][jj][2][q]);
          float ov = sigm(acc[mt][jj][3][q]);
          float c = fv * cfr[mt][jj][q] + iv * gv;
          cfr[mt][jj][q] = c;
          u16 hb = f2bf(ov * tanh_(c));
          int row = mt * 16 + lhi * 4 + q;
          hlds[nxt][((row << 5) + ((colb >> 3) ^ (row & 7))) * 8 + (colb & 7)] = hb;
          a.Y[((size_t)(bb + row) * TT + ty) * a.ycols + yoff + colb] = hb;
        }
      }
    // stage x for step s+1
    if (s + 1 < TT){
      int row = tid >> 4, c16 = tid & 15;
      if (c16 < 12){
        int tsrc = DEC ? s : (dir ? (TT - 2 - s) : (s + 1));
        xT[nxt][row * 32 + c16] = f2bf(a.x[((size_t)(a.gb0 + bb + row) * TT + tsrc) * 12 + c16]);
      }
    }
    __syncthreads();
  }
}

// ---------------- G-input recurrence (enc-l1, dec-l1) ----------------

struct RGArgs {
  const u16* G0; const u16* G1;
  const u16* W0; const u16* W1;
  u16* sH0; u16* sH1;
  float* sC0; float* sC1;
  const u16* Wo; const float* bout; float* outp;  // OUTP: [row][TT][12], group-local
  int t0, t1, nb, btiles;
};

template<int OUTP>
__global__ __launch_bounds__(512, 2) void k_rg(RGArgs a){
  const int bx = blockIdx.x;
  const int dir = bx / a.nb;
  const int bb = (bx - dir * a.nb) * 32;
  const int tid = threadIdx.x;
  const int lane = tid & 63, w = tid >> 6;
  const int l15 = lane & 15, lhi = lane >> 4;
  const u16* G  = dir ? a.G1 : a.G0;
  const u16* Whh = dir ? a.W1 : a.W0;
  u16* sH = dir ? a.sH1 : a.sH0;
  float* sC = dir ? a.sC1 : a.sC0;

  __shared__ __align__(16) u16 hlds[2][32 * 256];

  const int b0buf = a.t0 & 1;
#pragma unroll
  for (int i = 0; i < 2; ++i){
    int idx = i * 512 + tid;
    int row = idx >> 5, sl = idx & 31;
    bf16x8_t v = *(const bf16x8_t*)(sH + (size_t)(bb + row) * 256 + sl * 8);
    *(bf16x8_t*)&hlds[b0buf][((row << 5) + (sl ^ (row & 7))) * 8] = v;
  }
  float cfr[2][2][4];
#pragma unroll
  for (int mt = 0; mt < 2; ++mt)
#pragma unroll
    for (int jj = 0; jj < 2; ++jj){
      int col = (w + 8 * jj) * 16 + l15;
#pragma unroll
      for (int q = 0; q < 4; ++q)
        cfr[mt][jj][q] = sC[(size_t)(bb + mt * 16 + lhi * 4 + q) * 256 + col];
    }
  bf16x8_t wo[8];
  float bo = 0.f;
  if (OUTP && w < 2){
#pragma unroll
    for (int ks = 0; ks < 8; ++ks)
      wo[ks] = *(const bf16x8_t*)(a.Wo + (size_t)l15 * 256 + ks * 32 + (lhi << 3));
    if (l15 < 12) bo = a.bout[l15];
  }
  __syncthreads();

  for (int s = a.t0; s < a.t1; ++s){
    const int cur = s & 1, nxt = cur ^ 1;
    if (OUTP && s > a.t0 && w < 2){
      f32x4_t oa = (f32x4_t){0.f, 0.f, 0.f, 0.f};
      int row = w * 16 + l15;
#pragma unroll
      for (int ks = 0; ks < 8; ++ks){
        bf16x8_t af = *(const bf16x8_t*)&hlds[cur][((row << 5) + ((ks * 4 + lhi) ^ (row & 7))) * 8];
        oa = __builtin_amdgcn_mfma_f32_16x16x32_bf16(af, wo[ks], oa, 0, 0, 0);
      }
      if (l15 < 12)
#pragma unroll
        for (int q = 0; q < 4; ++q)
          a.outp[((size_t)(bb + w * 16 + lhi * 4 + q) * TT + (s - 1)) * 12 + l15] = oa[q] + bo;
    }
    f32x4_t acc[2][2][4];
#pragma unroll
    for (int mt = 0; mt < 2; ++mt)
#pragma unroll
      for (int jj = 0; jj < 2; ++jj)
#pragma unroll
        for (int g = 0; g < 4; ++g){
          int btile = (bb >> 4) + mt;
          int ntile = g * 16 + w + 8 * jj;
          bf16x4_t gv = *(const bf16x4_t*)(G + ((((size_t)(s - a.t0) * a.btiles + btile) * 64 + ntile) * 64 + lane) * 4);
          acc[mt][jj][g] = cvt4(gv);
        }
#pragma unroll
    for (int ks = 0; ks < 8; ++ks){
      int sl = ks * 4 + lhi;
      bf16x8_t af0 = *(const bf16x8_t*)&hlds[cur][((l15 << 5) + (sl ^ (l15 & 7))) * 8];
      int r1 = 16 + l15;
      bf16x8_t af1 = *(const bf16x8_t*)&hlds[cur][((r1 << 5) + (sl ^ (r1 & 7))) * 8];
      bf16x8_t bfr[2][4];
#pragma unroll
      for (int jj = 0; jj < 2; ++jj)
#pragma unroll
        for (int g = 0; g < 4; ++g)
          bfr[jj][g] = *(const bf16x8_t*)(Whh + (size_t)(g * 256 + (w + 8 * jj) * 16 + l15) * 256 + ks * 32 + (lhi << 3));
#pragma unroll
      for (int jj = 0; jj < 2; ++jj)
#pragma unroll
        for (int g = 0; g < 4; ++g){
          acc[0][jj][g] = __builtin_amdgcn_mfma_f32_16x16x32_bf16(af0, bfr[jj][g], acc[0][jj][g], 0, 0, 0);
          acc[1][jj][g] = __builtin_amdgcn_mfma_f32_16x16x32_bf16(af1, bfr[jj][g], acc[1][jj][g], 0, 0, 0);
        }
    }
#pragma unroll
    for (int mt = 0; mt < 2; ++mt)
#pragma unroll
      for (int jj = 0; jj < 2; ++jj){
        int colb = (w + 8 * jj) * 16 + l15;
#pragma unroll
        for (int q = 0; q < 4; ++q){
          float iv = sigm(acc[mt][jj][0][q]);
          float fv = sigm(acc[mt][jj][1][q]);
          float gv = tanh_(acc[mt][jj][2][q]);
          float ov = sigm(acc[mt][jj][3][q]);
          float c = fv * cfr[mt][jj][q] + iv * gv;
          cfr[mt][jj][q] = c;
          u16 hb = f2bf(ov * tanh_(c));
          int row = mt * 16 + lhi * 4 + q;
          hlds[nxt][((row << 5) + ((colb >> 3) ^ (row & 7))) * 8 + (colb & 7)] = hb;
        }
      }
    __syncthreads();
  }

  const int ebuf = a.t1 & 1;
  if (OUTP && w < 2){
    f32x4_t oa = (f32x4_t){0.f, 0.f, 0.f, 0.f};
    int row = w * 16 + l15;
#pragma unroll
    for (int ks = 0; ks < 8; ++ks){
      bf16x8_t af = *(const bf16x8_t*)&hlds[ebuf][((row << 5) + ((ks * 4 + lhi) ^ (row & 7))) * 8];
      oa = __builtin_amdgcn_mfma_f32_16x16x32_bf16(af, wo[ks], oa, 0, 0, 0);
    }
    if (l15 < 12)
#pragma unroll
      for (int q = 0; q < 4; ++q)
        a.outp[((size_t)(bb + w * 16 + lhi * 4 + q) * TT + (a.t1 - 1)) * 12 + l15] = oa[q] + bo;
  }
  // state writeback
#pragma unroll
  for (int i = 0; i < 2; ++i){
    int idx = i * 512 + tid;
    int row = idx >> 5, sl = idx & 31;
    bf16x8_t v = *(const bf16x8_t*)&hlds[ebuf][((row << 5) + (sl ^ (row & 7))) * 8];
    *(bf16x8_t*)(sH + (size_t)(bb + row) * 256 + sl * 8) = v;
  }
#pragma unroll
  for (int mt = 0; mt < 2; ++mt)
#pragma unroll
    for (int jj = 0; jj < 2; ++jj){
      int col = (w + 8 * jj) * 16 + l15;
#pragma unroll
      for (int q = 0; q < 4; ++q)
        sC[(size_t)(bb + mt * 16 + lhi * 4 + q) * 256 + col] = cfr[mt][jj][q];
    }
}

// ---------------- mid kernels (full batch, small) ----------------

__global__ void k_mulv(const u16* sH0, const u16* sH1,
                       const float* Wmu, const float* bmu,
                       const float* Wlv, const float* blv, float* mulv){
  int i = blockIdx.x * blockDim.x + threadIdx.x;
  if (i >= BFULL * 128) return;
  int b = i >> 7, j = i & 127;
  const float* W = (j < 64) ? (Wmu + (size_t)j * 512) : (Wlv + (size_t)(j - 64) * 512);
  float s = (j < 64) ? bmu[j] : blv[j - 64];
  for (int k = 0; k < 256; ++k) s += bf2f(sH0[(size_t)b * 256 + k]) * W[k];
  for (int k = 0; k < 256; ++k) s += bf2f(sH1[(size_t)b * 256 + k]) * W[256 + k];
  mulv[i] = s;
}

__global__ void k_sample(const float* mulv, const float* eps, const int* labels, const float* emb,
                         float* out_mu, float* out_lv, float* out_z, float* zcf){
  int i = blockIdx.x * blockDim.x + threadIdx.x;
  if (i >= BFULL * 128) return;
  int b = i >> 7, j = i & 127;
  if (j < 64){
    float mu = mulv[b * 128 + j];
    float lv = mulv[b * 128 + 64 + j];
    float z = mu + eps[b * 64 + j] * __expf(0.5f * lv);
    out_mu[b * 64 + j] = mu;
    out_lv[b * 64 + j] = lv;
    out_z[b * 64 + j] = z;
    zcf[i] = z;
  } else if (j < 72){
    zcf[i] = emb[labels[b] * 8 + (j - 64)];
  } else {
    zcf[i] = 0.f;
  }
}

__global__ void k_hc(const float* zcf, const float* Whid, const float* bhid,
                     const float* Wcell, const float* bcell, float* HC){
  int i = blockIdx.x * blockDim.x + threadIdx.x;
  if (i >= BFULL * 1024) return;
  int b = i >> 10, n = i & 1023;
  const float* W; float s;
  if (n < 512){ W = Whid + (size_t)n * 72; s = bhid[n]; }
  else        { W = Wcell + (size_t)(n - 512) * 72; s = bcell[n - 512]; }
  for (int k = 0; k < 72; ++k) s += zcf[b * 128 + k] * W[k];
  HC[i] = s;
}

__global__ void k_zconst(const float* zcf, const float* dWih0,
                         const float* dbih0, const float* dbhh0, float* zconst){
  int i = blockIdx.x * blockDim.x + threadIdx.x;
  if (i >= BFULL * 1024) return;
  int b = i >> 10, n = i & 1023;
  float s = dbih0[n] + dbhh0[n];
  const float* W = dWih0 + (size_t)n * 84 + 12;
  for (int k = 0; k < 72; ++k) s += zcf[b * 128 + k] * W[k];
  zconst[i] = s;
}

// zconst -> MFMA C-frag layout bf16: [btile(BFULL/16)][ntile 64][lane 64][4]
__global__ void k_zfrag(const float* zconst, u16* zcF){
  int i = blockIdx.x * blockDim.x + threadIdx.x;
  if (i >= BFULL * GH) return;
  int q = i & 3, ln = (i >> 2) & 63, nt = (i >> 8) & 63, bt = i >> 14;
  int r = bt * 16 + (ln >> 4) * 4 + q;
  int col = nt * 16 + (ln & 15);
  zcF[i] = f2bf(zconst[(size_t)r * GH + col]);
}

// faithful torch .view(NL, B, H) on [B, NL*H]
__global__ void k_dec_init(const float* HC, u16* h0, float* c0, u16* h1, float* c1){
  int i = blockIdx.x * blockDim.x + threadIdx.x;
  if (i >= BFULL * 256) return;
  int b = i >> 8, h = i & 255;
  int col = (b & 1) * 256 + h;
  int r0 = b >> 1;
  int r1 = 256 + (b >> 1);
  h0[i] = f2bf(HC[(size_t)r0 * 1024 + col]);
  c0[i] =      HC[(size_t)r0 * 1024 + 512 + col];
  h1[i] = f2bf(HC[(size_t)r1 * 1024 + col]);
  c1[i] =      HC[(size_t)r1 * 1024 + 512 + col];
}

// ---------------- host ----------------

static inline size_t alignup(size_t x){ return (x + 255) & ~(size_t)255; }

extern "C" void kernel_launch(void* const* d_in, const int* in_sizes, int n_in,
                              void* d_out, int out_size, void* d_ws, size_t ws_size,
                              hipStream_t stream){
  const float* x      = (const float*)d_in[0];
  const int*   labels = (const int*)  d_in[1];
  const float* eps    = (const float*)d_in[2];
  const float* emb    = (const float*)d_in[3];
  const float* Wih0f = (const float*)d_in[4],  *Whh0f = (const float*)d_in[5];
  const float* bih0f = (const float*)d_in[6],  *bhh0f = (const float*)d_in[7];
  const float* Wih0b = (const float*)d_in[8],  *Whh0b = (const float*)d_in[9];
  const float* bih0b = (const float*)d_in[10], *bhh0b = (const float*)d_in[11];
  const float* Wih1f = (const float*)d_in[12], *Whh1f = (const float*)d_in[13];
  const float* bih1f = (const float*)d_in[14], *bhh1f = (const float*)d_in[15];
  const float* Wih1b = (const float*)d_in[16], *Whh1b = (const float*)d_in[17];
  const float* bih1b = (const float*)d_in[18], *bhh1b = (const float*)d_in[19];
  const float* Wmu = (const float*)d_in[20], *bmu = (const float*)d_in[21];
  const float* Wlv = (const float*)d_in[22], *blv = (const float*)d_in[23];
  const float* Whid = (const float*)d_in[24], *bhid = (const float*)d_in[25];
  const float* Wcell = (const float*)d_in[26], *bcell = (const float*)d_in[27];
  const float* dWih0 = (const float*)d_in[28], *dWhh0 = (const float*)d_in[29];
  const float* dbih0 = (const float*)d_in[30], *dbhh0 = (const float*)d_in[31];
  const float* dWih1 = (const float*)d_in[32], *dWhh1 = (const float*)d_in[33];
  const float* dbih1 = (const float*)d_in[34], *dbhh1 = (const float*)d_in[35];
  const float* Wout = (const float*)d_in[36], *bout = (const float*)d_in[37];

  float* out = (float*)d_out;
  float* out_mu = out + (size_t)BFULL * TT * 12;
  float* out_lv = out_mu + (size_t)BFULL * 64;
  float* out_z  = out_lv + (size_t)BFULL * 64;

  // ---- fixed ws bytes ----
  size_t wbytes = 3 * alignup(1024 * 32 * 2) + alignup(16 * 256 * 2)
                + 7 * alignup((size_t)1024 * 256 * 2) + 2 * alignup((size_t)1024 * 512 * 2)
                + 5 * alignup(1024 * 4);
  size_t sbytes = alignup((size_t)2 * BFULL * 256 * 2) + alignup((size_t)2 * BFULL * 256 * 4)
                + alignup((size_t)BFULL * 256 * 2) + alignup((size_t)BFULL * 256 * 4)
                + alignup((size_t)BFULL * 256 * 2) + alignup((size_t)BFULL * 256 * 4)
                + 2 * alignup((size_t)BFULL * 128 * 4) + 2 * alignup((size_t)BFULL * 1024 * 4)
                + alignup((size_t)BFULL * 1024 * 2);
  size_t fixedB = wbytes + sbytes + (1 << 20);

  int Bg = 128, Tc = 2;
  {
    const int bgs[3] = {512, 256, 128};
    const int tcs[5] = {24, 16, 12, 8, 4};
    bool found = false;
    for (int bi = 0; bi < 3 && !found; ++bi)
      for (int ti = 0; ti < 5 && !found; ++ti){
        size_t need = fixedB + alignup((size_t)bgs[bi] * TT * 512 * 2)
                    + 2 * alignup((size_t)tcs[ti] * bgs[bi] * GH * 2);
        if (need <= ws_size){ Bg = bgs[bi]; Tc = tcs[ti]; found = true; }
      }
  }
  int bgLog = 31 - __builtin_clz((unsigned)Bg);
  const int nGroups = BFULL / Bg;
  const int nb = Bg / 32;

  // ---- ws layout ----
  char* ws = (char*)d_ws; size_t off = 0;
  auto alloc = [&](size_t bytes)->char*{ char* p = ws + off; off += alignup(bytes); return p; };

  u16* W0f_b  = (u16*)alloc(1024 * 32 * 2);
  u16* W0b_b  = (u16*)alloc(1024 * 32 * 2);
  u16* dWx_b  = (u16*)alloc(1024 * 32 * 2);
  u16* Wo_b   = (u16*)alloc(16 * 256 * 2);
  u16* Whh0f_b = (u16*)alloc((size_t)1024 * 256 * 2);
  u16* Whh0b_b = (u16*)alloc((size_t)1024 * 256 * 2);
  u16* Whh1f_b = (u16*)alloc((size_t)1024 * 256 * 2);
  u16* Whh1b_b = (u16*)alloc((size_t)1024 * 256 * 2);
  u16* dWhh0_b = (u16*)alloc((size_t)1024 * 256 * 2);
  u16* dWhh1_b = (u16*)alloc((size_t)1024 * 256 * 2);
  u16* dWih1_b = (u16*)alloc((size_t)1024 * 256 * 2);
  u16* Wih1f_b = (u16*)alloc((size_t)1024 * 512 * 2);
  u16* Wih1b_b = (u16*)alloc((size_t)1024 * 512 * 2);
  float* b0f = (float*)alloc(1024 * 4);
  float* b0b = (float*)alloc(1024 * 4);
  float* b1f = (float*)alloc(1024 * 4);
  float* b1b = (float*)alloc(1024 * 4);
  float* db1 = (float*)alloc(1024 * 4);
  u16*  sHe1 = (u16*)alloc((size_t)2 * BFULL * 256 * 2);
  float* sCe1 = (float*)alloc((size_t)2 * BFULL * 256 * 4);
  u16*  dh0 = (u16*)alloc((size_t)BFULL * 256 * 2);
  float* dc0 = (float*)alloc((size_t)BFULL * 256 * 4);
  u16*  dh1 = (u16*)alloc((size_t)BFULL * 256 * 2);
  float* dc1 = (float*)alloc((size_t)BFULL * 256 * 4);
  float* mulv = (float*)alloc((size_t)BFULL * 128 * 4);
  float* zcf  = (float*)alloc((size_t)BFULL * 128 * 4);
  float* HC   = (float*)alloc((size_t)BFULL * 1024 * 4);
  float* zconst = (float*)alloc((size_t)BFULL * 1024 * 4);
  u16*  zcF   = (u16*)alloc((size_t)BFULL * 1024 * 2);
  u16* y0  = (u16*)alloc((size_t)Bg * TT * 512 * 2);   // also aliased as y0d in decoder
  u16* Gf  = (u16*)alloc((size_t)Tc * Bg * GH * 2);
  u16* Gb  = (u16*)alloc((size_t)Tc * Bg * GH * 2);
  u16* y0d = y0;

  auto cvt = [&](const float* src, u16* dst, int N, int srcK, int useK, int Np, int Kp){
    int tot = Np * Kp;
    k_cvt_pad<<<(tot + 255) / 256, 256, 0, stream>>>(src, dst, N, srcK, useK, Np, Kp);
  };
  auto bsum = [&](const float* a, const float* b, float* o){
    k_bias_sum<<<4, 256, 0, stream>>>(a, b, o, 1024);
  };
  auto zero = [&](void* p, size_t nf){
    k_zero<<<(int)((nf + 255) / 256), 256, 0, stream>>>((float*)p, (int)nf);
  };
  auto proj = [&](const u16* A, int Akp, int K, const u16* W, const float* cb,
                  u16* G, int t0, int tc, int rev){
    ProjArgs pa; pa.A = A; pa.W = W; pa.colbias = cb; pa.G = G;
    pa.Akp = Akp; pa.K = K; pa.t0 = t0; pa.rev = rev; pa.Bg = Bg; pa.bgLog = bgLog;
    dim3 grid(tc * (Bg / 128), 8);
    k_proj<64><<<grid, 256, 0, stream>>>(pa);
  };

  // ---- weight prep ----
  cvt(Wih0f, W0f_b, 1024, 20, 20, 1024, 32);
  cvt(Wih0b, W0b_b, 1024, 20, 20, 1024, 32);
  cvt(dWih0, dWx_b, 1024, 84, 12, 1024, 32);
  cvt(Wout,  Wo_b,  12, 256, 256, 16, 256);
  cvt(Whh0f, Whh0f_b, 1024, 256, 256, 1024, 256);
  cvt(Whh0b, Whh0b_b, 1024, 256, 256, 1024, 256);
  cvt(Whh1f, Whh1f_b, 1024, 256, 256, 1024, 256);
  cvt(Whh1b, Whh1b_b, 1024, 256, 256, 1024, 256);
  cvt(dWhh0, dWhh0_b, 1024, 256, 256, 1024, 256);
  cvt(dWhh1, dWhh1_b, 1024, 256, 256, 1024, 256);
  cvt(dWih1, dWih1_b, 1024, 256, 256, 1024, 256);
  cvt(Wih1f, Wih1f_b, 1024, 512, 512, 1024, 512);
  cvt(Wih1b, Wih1b_b, 1024, 512, 512, 1024, 512);
  bsum(bih0f, bhh0f, b0f);
  bsum(bih0b, bhh0b, b0b);
  bsum(bih1f, bhh1f, b1f);
  bsum(bih1b, bhh1b, b1b);
  bsum(dbih1, dbhh1, db1);

  zero(sHe1, (size_t)2 * BFULL * 256 / 2);
  zero(sCe1, (size_t)2 * BFULL * 256);

  // ---- encoder ----
  for (int g = 0; g < nGroups; ++g){
    int gb0 = g * Bg;
    RXArgs rx = {};
    rx.x = x; rx.labels = labels; rx.emb = emb;
    rx.cb0 = b0f; rx.cb1 = b0b;
    rx.Wx0 = W0f_b; rx.Wx1 = W0b_b;
    rx.Wh0 = Whh0f_b; rx.Wh1 = Whh0b_b;
    rx.Y = y0; rx.ycols = 512; rx.yoff0 = 0; rx.yoff1 = 256;
    rx.gb0 = gb0; rx.nb = nb;
    k_rx<0><<<2 * nb, 512, 0, stream>>>(rx);
    for (int t0 = 0; t0 < TT; t0 += Tc){
      int t1 = (t0 + Tc < TT) ? t0 + Tc : TT; int tc = t1 - t0;
      proj(y0, 512, 512, Wih1f_b, b1f, Gf, t0, tc, 0);
      proj(y0, 512, 512, Wih1b_b, b1b, Gb, t0, tc, 1);
      RGArgs rg = {};
      rg.G0 = Gf; rg.G1 = Gb; rg.W0 = Whh1f_b; rg.W1 = Whh1b_b;
      rg.sH0 = sHe1 + (size_t)gb0 * 256;
      rg.sH1 = sHe1 + (size_t)BFULL * 256 + (size_t)gb0 * 256;
      rg.sC0 = sCe1 + (size_t)gb0 * 256;
      rg.sC1 = sCe1 + (size_t)BFULL * 256 + (size_t)gb0 * 256;
      rg.t0 = t0; rg.t1 = t1; rg.nb = nb; rg.btiles = Bg >> 4;
      k_rg<0><<<2 * nb, 512, 0, stream>>>(rg);
    }
  }

  // ---- VAE head + decoder init ----
  k_mulv<<<(BFULL * 128) / 256, 256, 0, stream>>>(sHe1, sHe1 + (size_t)BFULL * 256,
                                                  Wmu, bmu, Wlv, blv, mulv);
  k_sample<<<(BFULL * 128) / 256, 256, 0, stream>>>(mulv, eps, labels, emb,
                                                    out_mu, out_lv, out_z, zcf);
  k_hc<<<(BFULL * 1024) / 256, 256, 0, stream>>>(zcf, Whid, bhid, Wcell, bcell, HC);
  k_zconst<<<(BFULL * 1024) / 256, 256, 0, stream>>>(zcf, dWih0, dbih0, dbhh0, zconst);
  k_zfrag<<<(BFULL * GH) / 256, 256, 0, stream>>>(zconst, zcF);
  k_dec_init<<<(BFULL * 256) / 256, 256, 0, stream>>>(HC, dh0, dc0, dh1, dc1);

  // ---- decoder ----
  for (int g = 0; g < nGroups; ++g){
    int gb0 = g * Bg;
    RXArgs rx = {};
    rx.x = x;
    rx.zcF = zcF + (size_t)gb0 * 1024;
    rx.Wx0 = dWx_b; rx.Wh0 = dWhh0_b;
    rx.dh = dh0 + (size_t)gb0 * 256; rx.dc = dc0 + (size_t)gb0 * 256;
    rx.Y = y0d; rx.ycols = 256; rx.yoff0 = 0;
    rx.gb0 = gb0; rx.nb = nb;
    k_rx<1><<<nb, 512, 0, stream>>>(rx);
    for (int t0 = 0; t0 < TT; t0 += Tc){
      int t1 = (t0 + Tc < TT) ? t0 + Tc : TT; int tc = t1 - t0;
      proj(y0d, 256, 256, dWih1_b, db1, Gf, t0, tc, 0);
      RGArgs rg = {};
      rg.G0 = Gf; rg.W0 = dWhh1_b;
      rg.sH0 = dh1 + (size_t)gb0 * 256;
      rg.sC0 = dc1 + (size_t)gb0 * 256;
      rg.Wo = Wo_b; rg.bout = bout;
      rg.outp = out + (size_t)gb0 * TT * 12;
      rg.t0 = t0; rg.t1 = t1; rg.nb = nb; rg.btiles = Bg >> 4;
      k_rg<1><<<nb, 512, 0, stream>>>(rg);
    }
  }
}